// Round 3
// baseline (10140.672 us; speedup 1.0000x reference)
//
#include <hip/hip_runtime.h>

#define BB 16
#define KD 128
#define ND 8000
#define DD 256
#define LMB 1000.0f

// ---------------- K1: projection  sdescr[b][k][d] = sum_n pinv[b][k][n]*descr[b][d][n]
// grid (16, 8 slices, 2 tensors), block 1024 = 1 block/CU. Tile: 128 k x 256 d, n-chunks of 40.
#define CH 40
#define CHW 44   // padded LDS row stride in words (stride ≡ 12 mod 32 -> full-bank-sweep b128, conflict-free)
#define NSL 8
#define NRG 1000
#define NCHK 25

// amdgpu_waves_per_eu(2,4): min 2 waves/EU -> VGPR cap 512/2 = 256. The kernel
// needs ~100 live VGPRs (acc[4][8] + fragments + prefetch); the default 64-VGPR
// budget (8 waves/EU target) spilled acc to scratch -> 33 GB of phantom HBM
// traffic (R1/R2 rocprof). Grid = 256 blocks = 1 block/CU, so real occupancy is
// 4 waves/EU regardless.
__global__ __attribute__((amdgpu_flat_work_group_size(1024, 1024), amdgpu_waves_per_eu(2, 4)))
void proj_kernel(
    const float* __restrict__ pinv_a, const float* __restrict__ descr_a,
    const float* __restrict__ pinv_b, const float* __restrict__ descr_b,
    float* __restrict__ sd_a, float* __restrict__ sd_b)
{
    const int b = blockIdx.x, slice = blockIdx.y, which = blockIdx.z;
    const float* P  = (which ? pinv_b  : pinv_a)  + (size_t)b * KD * ND;
    const float* Dm = (which ? descr_b : descr_a) + (size_t)b * DD * ND;
    float* outp = (which ? sd_b : sd_a) + (size_t)b * KD * DD;

    __shared__ float kbuf[KD][CHW];
    __shared__ float dbuf[DD][CHW];

    const int tid = threadIdx.x;
    const int tk = tid >> 5, td = tid & 31;

    // staging plan: 3840 float4 per chunk; u=0..2 always valid, u=3 only tid<768
    const float* gsrc[4];
    float* ldst[4];
    const bool v3 = (tid < 768);
    #pragma unroll
    for (int u = 0; u < 4; ++u) {
        int i = tid + u * 1024;
        if (i < 3840) {
            if (i < 1280) {
                int r = i / 10, c = i % 10;
                gsrc[u] = P + (size_t)r * ND + c * 4;
                ldst[u] = &kbuf[r][c * 4];
            } else {
                int j = i - 1280;
                int r = j / 10, c = j % 10;
                gsrc[u] = Dm + (size_t)r * ND + c * 4;
                ldst[u] = &dbuf[r][c * 4];
            }
        } else { gsrc[u] = P; ldst[u] = &kbuf[0][0]; }
    }
    float4 pf0, pf1, pf2, pf3;

    float acc[4][8];
    #pragma unroll
    for (int i = 0; i < 4; ++i)
        #pragma unroll
        for (int j = 0; j < 8; ++j) acc[i][j] = 0.f;

    const int n0 = slice * NRG;
    // preload + store chunk 0
    pf0 = *(const float4*)(gsrc[0] + n0);
    pf1 = *(const float4*)(gsrc[1] + n0);
    pf2 = *(const float4*)(gsrc[2] + n0);
    if (v3) pf3 = *(const float4*)(gsrc[3] + n0);
    *(float4*)ldst[0] = pf0;
    *(float4*)ldst[1] = pf1;
    *(float4*)ldst[2] = pf2;
    if (v3) *(float4*)ldst[3] = pf3;
    __syncthreads();

    for (int ch = 0; ch < NCHK; ++ch) {
        if (ch + 1 < NCHK) {
            int nb = n0 + (ch + 1) * CH;
            pf0 = *(const float4*)(gsrc[0] + nb);
            pf1 = *(const float4*)(gsrc[1] + nb);
            pf2 = *(const float4*)(gsrc[2] + nb);
            if (v3) pf3 = *(const float4*)(gsrc[3] + nb);
        }
        #pragma unroll
        for (int n4 = 0; n4 < 10; ++n4) {
            float4 kv[4];
            #pragma unroll
            for (int i = 0; i < 4; ++i) kv[i] = *(const float4*)&kbuf[tk + 32 * i][n4 * 4];
            #pragma unroll
            for (int jh = 0; jh < 2; ++jh) {
                float4 dv[4];
                #pragma unroll
                for (int j4 = 0; j4 < 4; ++j4)
                    dv[j4] = *(const float4*)&dbuf[td + 32 * (jh * 4 + j4)][n4 * 4];
                #pragma unroll
                for (int i = 0; i < 4; ++i)
                    #pragma unroll
                    for (int j4 = 0; j4 < 4; ++j4)
                        acc[i][jh * 4 + j4] += kv[i].x * dv[j4].x + kv[i].y * dv[j4].y
                                             + kv[i].z * dv[j4].z + kv[i].w * dv[j4].w;
            }
        }
        __syncthreads();
        if (ch + 1 < NCHK) {
            *(float4*)ldst[0] = pf0;
            *(float4*)ldst[1] = pf1;
            *(float4*)ldst[2] = pf2;
            if (v3) *(float4*)ldst[3] = pf3;
        }
        __syncthreads();
    }

    #pragma unroll
    for (int i = 0; i < 4; ++i)
        #pragma unroll
        for (int j = 0; j < 8; ++j)
            atomicAdd(&outp[(size_t)(tk + 32 * i) * DD + td + 32 * j], acc[i][j]);
}

// ---------------- K2: masks (lambda folded in).  lm_ab[b][i][k] from (gb=eb[i], ga=ea[k])
__global__ __launch_bounds__(256) void mask_kernel(
    const float* __restrict__ ea_g, const float* __restrict__ eb_g,
    float* __restrict__ lm_ab, float* __restrict__ lm_ba)
{
    const int b = blockIdx.x, tid = threadIdx.x;
    __shared__ float ta[KD], ua[KD], tb[KD], ub[KD];
    __shared__ float red[256];
    float e = (tid < KD) ? ea_g[b * KD + tid] : eb_g[b * KD + (tid - KD)];
    red[tid] = e;
    __syncthreads();
    for (int s = 128; s > 0; s >>= 1) {
        if (tid < s) red[tid] = fmaxf(red[tid], red[tid + s]);
        __syncthreads();
    }
    float is = 1.0f / red[0];
    float g = e * is;
    float den = 1.0f / (g * g + 1.0f);
    if (tid < KD) { ta[tid] = g * den; ua[tid] = den; }
    else          { tb[tid - KD] = g * den; ub[tid - KD] = den; }
    __syncthreads();
    for (int idx = tid; idx < KD * KD; idx += 256) {
        int i = idx >> 7, kc = idx & 127;
        float re = tb[i] - ta[kc], im = ub[i] - ua[kc];
        lm_ab[(size_t)b * KD * KD + idx] = LMB * (re * re + im * im);
        float re2 = ta[i] - tb[kc], im2 = ua[i] - ub[kc];
        lm_ba[(size_t)b * KD * KD + idx] = LMB * (re2 * re2 + im2 * im2);
    }
}

// ---------------- K3: Grams. m=0: AA_aa(Sa,Sa) m=1: AA_bb(Sb,Sb) m=2: AA_ba(Sb,Sa)
// AA[m][b][k][l] = sum_d X[k][d]*Y[l][d]
__global__ __attribute__((amdgpu_flat_work_group_size(1024, 1024), amdgpu_waves_per_eu(2, 8)))
void gram_kernel(
    const float* __restrict__ sd_a, const float* __restrict__ sd_b,
    float* __restrict__ AA)
{
    const int b = blockIdx.x, m = blockIdx.y;
    const float* X = (m == 0) ? sd_a : sd_b;
    const float* Y = (m == 2) ? sd_a : X;
    X += (size_t)b * KD * DD;
    Y += (size_t)b * KD * DD;
    float* outp = AA + ((size_t)m * BB + b) * KD * KD;

    __shared__ float Xs[KD][68], Ys[KD][68];
    const int tid = threadIdx.x;
    const int kq = tid >> 5, lq = tid & 31;
    float acc[4][4];
    #pragma unroll
    for (int i = 0; i < 4; ++i)
        #pragma unroll
        for (int j = 0; j < 4; ++j) acc[i][j] = 0.f;

    for (int chn = 0; chn < 4; ++chn) {
        int d0 = chn * 64;
        #pragma unroll
        for (int u = 0; u < 4; ++u) {
            int i = tid + u * 1024;           // 4096 float4s: X 2048 then Y 2048
            int half = i >> 11, rem = i & 2047;
            int r = rem >> 4, c = rem & 15;
            const float* src = half ? Y : X;
            float4 v = *(const float4*)(src + (size_t)r * DD + d0 + c * 4);
            if (half) *(float4*)&Ys[r][c * 4] = v;
            else      *(float4*)&Xs[r][c * 4] = v;
        }
        __syncthreads();
        #pragma unroll
        for (int d4 = 0; d4 < 16; ++d4) {
            float4 xv[4], yv[4];
            #pragma unroll
            for (int i = 0; i < 4; ++i) xv[i] = *(const float4*)&Xs[kq + 32 * i][d4 * 4];
            #pragma unroll
            for (int j = 0; j < 4; ++j) yv[j] = *(const float4*)&Ys[lq + 32 * j][d4 * 4];
            #pragma unroll
            for (int i = 0; i < 4; ++i)
                #pragma unroll
                for (int j = 0; j < 4; ++j)
                    acc[i][j] += xv[i].x * yv[j].x + xv[i].y * yv[j].y
                               + xv[i].z * yv[j].z + xv[i].w * yv[j].w;
        }
        __syncthreads();
    }
    #pragma unroll
    for (int i = 0; i < 4; ++i)
        #pragma unroll
        for (int j = 0; j < 4; ++j)
            outp[(size_t)(kq + 32 * i) * KD + lq + 32 * j] = acc[i][j];
}

// ---------------- K4: Gauss-Jordan in-place inversion (SPD, no pivoting).
// grid (16, 2): which=0 -> inv(AA_aa), which=1 -> inv(AA_bb). 512 threads.
__global__ __launch_bounds__(512) void invert_kernel(
    const float* __restrict__ AA, float* __restrict__ Hout)
{
    const int b = blockIdx.x, which = blockIdx.y;
    const float* src = AA + ((size_t)which * BB + b) * KD * KD;
    float* dst = Hout + ((size_t)which * BB + b) * KD * KD;
    __shared__ float A[KD][KD + 1];
    const int tid = threadIdx.x;
    for (int u = 0; u < 32; ++u) {
        int i = tid + u * 512;
        A[i >> 7][i & 127] = src[i];
    }
    __syncthreads();
    const int c = tid & 127, igrp = tid >> 7;
    for (int j = 0; j < 128; ++j) {
        float pv = 1.0f / A[j][j];
        if (tid < 128 && tid != j) A[tid][j] = -A[tid][j] * pv;  // phase 1: column j
        __syncthreads();
        float rowv = A[j][c];
        if (c != j) {                                            // phase 2: rank-1 update
            int i0 = igrp * 32;
            #pragma unroll 8
            for (int t = 0; t < 32; ++t) {
                int i = i0 + t;
                if (i != j) A[i][c] += A[i][j] * rowv;
            }
        }
        __syncthreads();
        if (tid < 128) A[j][tid] = (tid == j) ? pv : A[j][tid] * pv;  // phase 3: row j
        __syncthreads();
    }
    for (int u = 0; u < 32; ++u) {
        int i = tid + u * 512;
        dst[i] = A[i >> 7][i & 127];
    }
}

// ---------------- K5: Neumann-series solve.
// which=0 (fmap_12): H=inv(AA_aa), lm=lm_ab, r_i = AA_ba[b][i][:]
// which=1 (fmap_21): H=inv(AA_bb), lm=lm_ba, r_i = AA_ba[b][:][i]
// x_i = sum_t (-1)^t (H*lmD_i)^t H r_i ; out[b][i][l] = x_i[l]
#define NTERMS 6
__global__ __launch_bounds__(512) void solve_kernel(
    const float* __restrict__ AAba, const float* __restrict__ lm_ab,
    const float* __restrict__ lm_ba, const float* __restrict__ Hmat,
    float* __restrict__ outp)
{
    const int b = blockIdx.x, cg = blockIdx.y, which = blockIdx.z;
    const float* Hm = Hmat + ((size_t)which * BB + b) * KD * KD;
    const float* lm = (which ? lm_ba : lm_ab) + (size_t)b * KD * KD;
    const float* Rs = AAba + (size_t)b * KD * KD;
    float* op = outp + ((size_t)which * BB + b) * KD * KD;
    const int i0 = cg * 32;

    __shared__ float Hs[KD][132];       // Hs[d][l]; H symmetric so Hs[d][l] == H[l][d]
    __shared__ float Zc[2][32][132];    // Zc[buf][ic][d]
    __shared__ float lms[32][132];      // lms[ic][l]

    const int tid = threadIdx.x;
    const int rq = tid & 31;            // rows l = rq*4 + rr
    const int cq = tid >> 5;            // 0..15, cols ic = cq*2 + cc

    #pragma unroll
    for (int u = 0; u < 8; ++u) {
        int idx = tid + u * 512;
        int d = idx >> 5, l4 = idx & 31;
        *(float4*)&Hs[d][l4 * 4] = *(const float4*)(Hm + (size_t)d * KD + l4 * 4);
    }
    #pragma unroll
    for (int u = 0; u < 8; ++u) {
        int idx = tid + u * 512;
        int ic = idx >> 7, l = idx & 127;
        lms[ic][l] = lm[(size_t)(i0 + ic) * KD + l];
    }
    if (which == 0) {
        #pragma unroll
        for (int u = 0; u < 8; ++u) {
            int idx = tid + u * 512;
            int ic = idx >> 7, d = idx & 127;
            Zc[0][ic][d] = Rs[(size_t)(i0 + ic) * KD + d];
        }
    } else {
        #pragma unroll
        for (int u = 0; u < 8; ++u) {
            int idx = tid + u * 512;
            int d = idx >> 5, ic = idx & 31;
            Zc[0][ic][d] = Rs[(size_t)d * KD + i0 + ic];
        }
    }
    __syncthreads();

    float xacc[4][2];
    #pragma unroll
    for (int rr = 0; rr < 4; ++rr) { xacc[rr][0] = 0.f; xacc[rr][1] = 0.f; }
    int cur = 0;
    for (int t = 0; t < NTERMS; ++t) {
        float zr[4][2];
        #pragma unroll
        for (int rr = 0; rr < 4; ++rr) { zr[rr][0] = 0.f; zr[rr][1] = 0.f; }
        #pragma unroll 8
        for (int d4 = 0; d4 < 32; ++d4) {
            float4 hv[4];
            #pragma unroll
            for (int dd = 0; dd < 4; ++dd)
                hv[dd] = *(const float4*)&Hs[d4 * 4 + dd][rq * 4];
            float4 wv[2];
            #pragma unroll
            for (int cc = 0; cc < 2; ++cc)
                wv[cc] = *(const float4*)&Zc[cur][cq * 2 + cc][d4 * 4];
            #pragma unroll
            for (int cc = 0; cc < 2; ++cc) {
                zr[0][cc] += hv[0].x * wv[cc].x + hv[1].x * wv[cc].y + hv[2].x * wv[cc].z + hv[3].x * wv[cc].w;
                zr[1][cc] += hv[0].y * wv[cc].x + hv[1].y * wv[cc].y + hv[2].y * wv[cc].z + hv[3].y * wv[cc].w;
                zr[2][cc] += hv[0].z * wv[cc].x + hv[1].z * wv[cc].y + hv[2].z * wv[cc].z + hv[3].z * wv[cc].w;
                zr[3][cc] += hv[0].w * wv[cc].x + hv[1].w * wv[cc].y + hv[2].w * wv[cc].z + hv[3].w * wv[cc].w;
            }
        }
        const float s = (t & 1) ? -1.f : 1.f;
        #pragma unroll
        for (int rr = 0; rr < 4; ++rr) {
            xacc[rr][0] += s * zr[rr][0];
            xacc[rr][1] += s * zr[rr][1];
        }
        if (t + 1 < NTERMS) {
            #pragma unroll
            for (int cc = 0; cc < 2; ++cc) {
                float4 lmv = *(const float4*)&lms[cq * 2 + cc][rq * 4];
                float4 w;
                w.x = lmv.x * zr[0][cc];
                w.y = lmv.y * zr[1][cc];
                w.z = lmv.z * zr[2][cc];
                w.w = lmv.w * zr[3][cc];
                *(float4*)&Zc[cur ^ 1][cq * 2 + cc][rq * 4] = w;
            }
            __syncthreads();
            cur ^= 1;
        }
    }
    #pragma unroll
    for (int cc = 0; cc < 2; ++cc) {
        float4 o;
        o.x = xacc[0][cc]; o.y = xacc[1][cc]; o.z = xacc[2][cc]; o.w = xacc[3][cc];
        *(float4*)(op + (size_t)(i0 + cq * 2 + cc) * KD + rq * 4) = o;
    }
}

extern "C" void kernel_launch(void* const* d_in, const int* in_sizes, int n_in,
                              void* d_out, int out_size, void* d_ws, size_t ws_size,
                              hipStream_t stream) {
    (void)in_sizes; (void)n_in; (void)out_size; (void)ws_size;
    const float* evals_a = (const float*)d_in[0];
    const float* pinv_a  = (const float*)d_in[1];
    const float* descr_a = (const float*)d_in[2];
    const float* evals_b = (const float*)d_in[3];
    const float* pinv_b  = (const float*)d_in[4];
    const float* descr_b = (const float*)d_in[5];
    float* out = (float*)d_out;
    float* ws = (float*)d_ws;

    const size_t SD = (size_t)BB * KD * DD;   // 524288
    const size_t MM = (size_t)BB * KD * KD;   // 262144
    float* sd_a  = ws;
    float* sd_b  = sd_a + SD;
    float* AA    = sd_b + SD;        // 3*MM: [0]=AA_aa [1]=AA_bb [2]=AA_ba
    float* lm_ab = AA + 3 * MM;
    float* lm_ba = lm_ab + MM;
    float* Hm    = lm_ba + MM;       // 2*MM

    hipMemsetAsync(sd_a, 0, 2 * SD * sizeof(float), stream);
    proj_kernel<<<dim3(BB, NSL, 2), 1024, 0, stream>>>(pinv_a, descr_a, pinv_b, descr_b, sd_a, sd_b);
    mask_kernel<<<dim3(BB), 256, 0, stream>>>(evals_a, evals_b, lm_ab, lm_ba);
    gram_kernel<<<dim3(BB, 3), 1024, 0, stream>>>(sd_a, sd_b, AA);
    invert_kernel<<<dim3(BB, 2), 512, 0, stream>>>(AA, Hm);
    solve_kernel<<<dim3(BB, 4, 2), 512, 0, stream>>>(AA + 2 * MM, lm_ab, lm_ba, Hm, out);
}

// Round 4
// 806.781 us; speedup vs baseline: 12.5693x; 12.5693x over previous
//
#include <hip/hip_runtime.h>

#define BB 16
#define KD 128
#define ND 8000
#define DD 256
#define LMB 1000.0f

// ---------------- K1: projection  sdescr[b][k][d] = sum_n pinv[b][k][n]*descr[b][d][n]
// grid (16, 8 slices, 2 tensors), block 1024. Tile: 128 k x 256 d, n-chunks of 40.
// Register-lean rewrite: ~52 live VGPRs (acc[4][8]=32 + 12 scalar operands + addrs),
// no pointer arrays, no reg prefetch -> cannot spill even at the default 64-VGPR budget.
#define CH 40
#define CHW 46   // gcd(46,32)=2 -> 2 lanes/bank on dv reads = conflict-free (m136)
#define NSL 8
#define NRG 1000
#define NCHK 25

__global__ __launch_bounds__(1024) void proj_kernel(
    const float* __restrict__ pinv_a, const float* __restrict__ descr_a,
    const float* __restrict__ pinv_b, const float* __restrict__ descr_b,
    float* __restrict__ sd_a, float* __restrict__ sd_b)
{
    const int b = blockIdx.x, slice = blockIdx.y, which = blockIdx.z;
    const float* P  = (which ? pinv_b  : pinv_a)  + (size_t)b * KD * ND;
    const float* Dm = (which ? descr_b : descr_a) + (size_t)b * DD * ND;
    float* outp = (which ? sd_b : sd_a) + (size_t)b * KD * DD;

    __shared__ float kbuf[KD][CHW];   // 128 x 46
    __shared__ float dbuf[DD][CHW];   // 256 x 46

    const int tid = threadIdx.x;
    const int tk = tid >> 5, td = tid & 31;
    const bool st = (tid < 960);      // 3840 float4 per chunk / 4 per thread

    float acc[4][8];
    #pragma unroll
    for (int i = 0; i < 4; ++i)
        #pragma unroll
        for (int j = 0; j < 8; ++j) acc[i][j] = 0.f;

    const int n0 = slice * NRG;

    for (int ch = 0; ch < NCHK; ++ch) {
        const int nb = n0 + ch * CH;
        if (st) {
            #pragma unroll
            for (int u = 0; u < 4; ++u) {
                int i = tid + u * 960;           // 0..3839
                int r = i / 10, c = i - r * 10;  // r: 0..383, c: 0..9
                const float* src = (r < KD) ? (P + (size_t)r * ND)
                                            : (Dm + (size_t)(r - KD) * ND);
                float4 v = *(const float4*)(src + nb + c * 4);
                float* drow = (r < KD) ? &kbuf[r][0] : &dbuf[r - KD][0];
                drow[c * 4 + 0] = v.x;
                drow[c * 4 + 1] = v.y;
                drow[c * 4 + 2] = v.z;
                drow[c * 4 + 3] = v.w;
            }
        }
        __syncthreads();

        for (int n = 0; n < CH; ++n) {
            float kv0 = kbuf[tk +  0][n];
            float kv1 = kbuf[tk + 32][n];
            float kv2 = kbuf[tk + 64][n];
            float kv3 = kbuf[tk + 96][n];
            float dv[8];
            #pragma unroll
            for (int j = 0; j < 8; ++j) dv[j] = dbuf[td + 32 * j][n];
            #pragma unroll
            for (int j = 0; j < 8; ++j) {
                acc[0][j] += kv0 * dv[j];
                acc[1][j] += kv1 * dv[j];
                acc[2][j] += kv2 * dv[j];
                acc[3][j] += kv3 * dv[j];
            }
        }
        __syncthreads();
    }

    #pragma unroll
    for (int i = 0; i < 4; ++i)
        #pragma unroll
        for (int j = 0; j < 8; ++j)
            atomicAdd(&outp[(size_t)(tk + 32 * i) * DD + td + 32 * j], acc[i][j]);
}

// ---------------- K2: masks (lambda folded in).  lm_ab[b][i][k] from (gb=eb[i], ga=ea[k])
__global__ __launch_bounds__(256) void mask_kernel(
    const float* __restrict__ ea_g, const float* __restrict__ eb_g,
    float* __restrict__ lm_ab, float* __restrict__ lm_ba)
{
    const int b = blockIdx.x, tid = threadIdx.x;
    __shared__ float ta[KD], ua[KD], tb[KD], ub[KD];
    __shared__ float red[256];
    float e = (tid < KD) ? ea_g[b * KD + tid] : eb_g[b * KD + (tid - KD)];
    red[tid] = e;
    __syncthreads();
    for (int s = 128; s > 0; s >>= 1) {
        if (tid < s) red[tid] = fmaxf(red[tid], red[tid + s]);
        __syncthreads();
    }
    float is = 1.0f / red[0];
    float g = e * is;
    float den = 1.0f / (g * g + 1.0f);
    if (tid < KD) { ta[tid] = g * den; ua[tid] = den; }
    else          { tb[tid - KD] = g * den; ub[tid - KD] = den; }
    __syncthreads();
    for (int idx = tid; idx < KD * KD; idx += 256) {
        int i = idx >> 7, kc = idx & 127;
        float re = tb[i] - ta[kc], im = ub[i] - ua[kc];
        lm_ab[(size_t)b * KD * KD + idx] = LMB * (re * re + im * im);
        float re2 = ta[i] - tb[kc], im2 = ua[i] - ub[kc];
        lm_ba[(size_t)b * KD * KD + idx] = LMB * (re2 * re2 + im2 * im2);
    }
}

// ---------------- K3: Grams. m=0: AA_aa(Sa,Sa) m=1: AA_bb(Sb,Sb) m=2: AA_ba(Sb,Sa)
// AA[m][b][k][l] = sum_d X[k][d]*Y[l][d]
__global__ __attribute__((amdgpu_flat_work_group_size(1024, 1024), amdgpu_waves_per_eu(2, 8)))
void gram_kernel(
    const float* __restrict__ sd_a, const float* __restrict__ sd_b,
    float* __restrict__ AA)
{
    const int b = blockIdx.x, m = blockIdx.y;
    const float* X = (m == 0) ? sd_a : sd_b;
    const float* Y = (m == 2) ? sd_a : X;
    X += (size_t)b * KD * DD;
    Y += (size_t)b * KD * DD;
    float* outp = AA + ((size_t)m * BB + b) * KD * KD;

    __shared__ float Xs[KD][68], Ys[KD][68];
    const int tid = threadIdx.x;
    const int kq = tid >> 5, lq = tid & 31;
    float acc[4][4];
    #pragma unroll
    for (int i = 0; i < 4; ++i)
        #pragma unroll
        for (int j = 0; j < 4; ++j) acc[i][j] = 0.f;

    for (int chn = 0; chn < 4; ++chn) {
        int d0 = chn * 64;
        #pragma unroll
        for (int u = 0; u < 4; ++u) {
            int i = tid + u * 1024;           // 4096 float4s: X 2048 then Y 2048
            int half = i >> 11, rem = i & 2047;
            int r = rem >> 4, c = rem & 15;
            const float* src = half ? Y : X;
            float4 v = *(const float4*)(src + (size_t)r * DD + d0 + c * 4);
            if (half) *(float4*)&Ys[r][c * 4] = v;
            else      *(float4*)&Xs[r][c * 4] = v;
        }
        __syncthreads();
        #pragma unroll
        for (int d4 = 0; d4 < 16; ++d4) {
            float4 xv[4], yv[4];
            #pragma unroll
            for (int i = 0; i < 4; ++i) xv[i] = *(const float4*)&Xs[kq + 32 * i][d4 * 4];
            #pragma unroll
            for (int j = 0; j < 4; ++j) yv[j] = *(const float4*)&Ys[lq + 32 * j][d4 * 4];
            #pragma unroll
            for (int i = 0; i < 4; ++i)
                #pragma unroll
                for (int j = 0; j < 4; ++j)
                    acc[i][j] += xv[i].x * yv[j].x + xv[i].y * yv[j].y
                               + xv[i].z * yv[j].z + xv[i].w * yv[j].w;
        }
        __syncthreads();
    }
    #pragma unroll
    for (int i = 0; i < 4; ++i)
        #pragma unroll
        for (int j = 0; j < 4; ++j)
            outp[(size_t)(kq + 32 * i) * KD + lq + 32 * j] = acc[i][j];
}

// ---------------- K4: Gauss-Jordan in-place inversion (SPD, no pivoting).
// grid (16, 2): which=0 -> inv(AA_aa), which=1 -> inv(AA_bb). 512 threads.
__global__ __launch_bounds__(512) void invert_kernel(
    const float* __restrict__ AA, float* __restrict__ Hout)
{
    const int b = blockIdx.x, which = blockIdx.y;
    const float* src = AA + ((size_t)which * BB + b) * KD * KD;
    float* dst = Hout + ((size_t)which * BB + b) * KD * KD;
    __shared__ float A[KD][KD + 1];
    const int tid = threadIdx.x;
    for (int u = 0; u < 32; ++u) {
        int i = tid + u * 512;
        A[i >> 7][i & 127] = src[i];
    }
    __syncthreads();
    const int c = tid & 127, igrp = tid >> 7;
    for (int j = 0; j < 128; ++j) {
        float pv = 1.0f / A[j][j];
        if (tid < 128 && tid != j) A[tid][j] = -A[tid][j] * pv;  // phase 1: column j
        __syncthreads();
        float rowv = A[j][c];
        if (c != j) {                                            // phase 2: rank-1 update
            int i0 = igrp * 32;
            #pragma unroll 8
            for (int t = 0; t < 32; ++t) {
                int i = i0 + t;
                if (i != j) A[i][c] += A[i][j] * rowv;
            }
        }
        __syncthreads();
        if (tid < 128) A[j][tid] = (tid == j) ? pv : A[j][tid] * pv;  // phase 3: row j
        __syncthreads();
    }
    for (int u = 0; u < 32; ++u) {
        int i = tid + u * 512;
        dst[i] = A[i >> 7][i & 127];
    }
}

// ---------------- K5: Neumann-series solve.
// which=0 (fmap_12): H=inv(AA_aa), lm=lm_ab, r_i = AA_ba[b][i][:]
// which=1 (fmap_21): H=inv(AA_bb), lm=lm_ba, r_i = AA_ba[b][:][i]
// x_i = sum_t (-1)^t (H*lmD_i)^t H r_i ; out[b][i][l] = x_i[l]
#define NTERMS 6
__global__ __launch_bounds__(512) void solve_kernel(
    const float* __restrict__ AAba, const float* __restrict__ lm_ab,
    const float* __restrict__ lm_ba, const float* __restrict__ Hmat,
    float* __restrict__ outp)
{
    const int b = blockIdx.x, cg = blockIdx.y, which = blockIdx.z;
    const float* Hm = Hmat + ((size_t)which * BB + b) * KD * KD;
    const float* lm = (which ? lm_ba : lm_ab) + (size_t)b * KD * KD;
    const float* Rs = AAba + (size_t)b * KD * KD;
    float* op = outp + ((size_t)which * BB + b) * KD * KD;
    const int i0 = cg * 32;

    __shared__ float Hs[KD][132];       // Hs[d][l]; H symmetric so Hs[d][l] == H[l][d]
    __shared__ float Zc[2][32][132];    // Zc[buf][ic][d]
    __shared__ float lms[32][132];      // lms[ic][l]

    const int tid = threadIdx.x;
    const int rq = tid & 31;            // rows l = rq*4 + rr
    const int cq = tid >> 5;            // 0..15, cols ic = cq*2 + cc

    #pragma unroll
    for (int u = 0; u < 8; ++u) {
        int idx = tid + u * 512;
        int d = idx >> 5, l4 = idx & 31;
        *(float4*)&Hs[d][l4 * 4] = *(const float4*)(Hm + (size_t)d * KD + l4 * 4);
    }
    #pragma unroll
    for (int u = 0; u < 8; ++u) {
        int idx = tid + u * 512;
        int ic = idx >> 7, l = idx & 127;
        lms[ic][l] = lm[(size_t)(i0 + ic) * KD + l];
    }
    if (which == 0) {
        #pragma unroll
        for (int u = 0; u < 8; ++u) {
            int idx = tid + u * 512;
            int ic = idx >> 7, d = idx & 127;
            Zc[0][ic][d] = Rs[(size_t)(i0 + ic) * KD + d];
        }
    } else {
        #pragma unroll
        for (int u = 0; u < 8; ++u) {
            int idx = tid + u * 512;
            int d = idx >> 5, ic = idx & 31;
            Zc[0][ic][d] = Rs[(size_t)d * KD + i0 + ic];
        }
    }
    __syncthreads();

    float xacc[4][2];
    #pragma unroll
    for (int rr = 0; rr < 4; ++rr) { xacc[rr][0] = 0.f; xacc[rr][1] = 0.f; }
    int cur = 0;
    for (int t = 0; t < NTERMS; ++t) {
        float zr[4][2];
        #pragma unroll
        for (int rr = 0; rr < 4; ++rr) { zr[rr][0] = 0.f; zr[rr][1] = 0.f; }
        #pragma unroll 8
        for (int d4 = 0; d4 < 32; ++d4) {
            float4 hv[4];
            #pragma unroll
            for (int dd = 0; dd < 4; ++dd)
                hv[dd] = *(const float4*)&Hs[d4 * 4 + dd][rq * 4];
            float4 wv[2];
            #pragma unroll
            for (int cc = 0; cc < 2; ++cc)
                wv[cc] = *(const float4*)&Zc[cur][cq * 2 + cc][d4 * 4];
            #pragma unroll
            for (int cc = 0; cc < 2; ++cc) {
                zr[0][cc] += hv[0].x * wv[cc].x + hv[1].x * wv[cc].y + hv[2].x * wv[cc].z + hv[3].x * wv[cc].w;
                zr[1][cc] += hv[0].y * wv[cc].x + hv[1].y * wv[cc].y + hv[2].y * wv[cc].z + hv[3].y * wv[cc].w;
                zr[2][cc] += hv[0].z * wv[cc].x + hv[1].z * wv[cc].y + hv[2].z * wv[cc].z + hv[3].z * wv[cc].w;
                zr[3][cc] += hv[0].w * wv[cc].x + hv[1].w * wv[cc].y + hv[2].w * wv[cc].z + hv[3].w * wv[cc].w;
            }
        }
        const float s = (t & 1) ? -1.f : 1.f;
        #pragma unroll
        for (int rr = 0; rr < 4; ++rr) {
            xacc[rr][0] += s * zr[rr][0];
            xacc[rr][1] += s * zr[rr][1];
        }
        if (t + 1 < NTERMS) {
            #pragma unroll
            for (int cc = 0; cc < 2; ++cc) {
                float4 lmv = *(const float4*)&lms[cq * 2 + cc][rq * 4];
                float4 w;
                w.x = lmv.x * zr[0][cc];
                w.y = lmv.y * zr[1][cc];
                w.z = lmv.z * zr[2][cc];
                w.w = lmv.w * zr[3][cc];
                *(float4*)&Zc[cur ^ 1][cq * 2 + cc][rq * 4] = w;
            }
            __syncthreads();
            cur ^= 1;
        }
    }
    #pragma unroll
    for (int cc = 0; cc < 2; ++cc) {
        float4 o;
        o.x = xacc[0][cc]; o.y = xacc[1][cc]; o.z = xacc[2][cc]; o.w = xacc[3][cc];
        *(float4*)(op + (size_t)(i0 + cq * 2 + cc) * KD + rq * 4) = o;
    }
}

extern "C" void kernel_launch(void* const* d_in, const int* in_sizes, int n_in,
                              void* d_out, int out_size, void* d_ws, size_t ws_size,
                              hipStream_t stream) {
    (void)in_sizes; (void)n_in; (void)out_size; (void)ws_size;
    const float* evals_a = (const float*)d_in[0];
    const float* pinv_a  = (const float*)d_in[1];
    const float* descr_a = (const float*)d_in[2];
    const float* evals_b = (const float*)d_in[3];
    const float* pinv_b  = (const float*)d_in[4];
    const float* descr_b = (const float*)d_in[5];
    float* out = (float*)d_out;
    float* ws = (float*)d_ws;

    const size_t SD = (size_t)BB * KD * DD;   // 524288
    const size_t MM = (size_t)BB * KD * KD;   // 262144
    float* sd_a  = ws;
    float* sd_b  = sd_a + SD;
    float* AA    = sd_b + SD;        // 3*MM: [0]=AA_aa [1]=AA_bb [2]=AA_ba
    float* lm_ab = AA + 3 * MM;
    float* lm_ba = lm_ab + MM;
    float* Hm    = lm_ba + MM;       // 2*MM

    hipMemsetAsync(sd_a, 0, 2 * SD * sizeof(float), stream);
    proj_kernel<<<dim3(BB, NSL, 2), 1024, 0, stream>>>(pinv_a, descr_a, pinv_b, descr_b, sd_a, sd_b);
    mask_kernel<<<dim3(BB), 256, 0, stream>>>(evals_a, evals_b, lm_ab, lm_ba);
    gram_kernel<<<dim3(BB, 3), 1024, 0, stream>>>(sd_a, sd_b, AA);
    invert_kernel<<<dim3(BB, 2), 512, 0, stream>>>(AA, Hm);
    solve_kernel<<<dim3(BB, 4, 2), 512, 0, stream>>>(AA + 2 * MM, lm_ab, lm_ba, Hm, out);
}

// Round 5
// 646.169 us; speedup vs baseline: 15.6935x; 1.2486x over previous
//
#include <hip/hip_runtime.h>

#define BB 16
#define KD 128
#define ND 8000
#define DD 256
#define LMB 1000.0f

typedef __attribute__((ext_vector_type(8))) short bf16x8;
typedef __attribute__((ext_vector_type(4))) float f32x4;
typedef unsigned short ushort_t;

// ---------------- K1: projection  sdescr[b][k][d] = sum_n pinv[b][k][n]*descr[b][d][n]
// Split-bf16 MFMA: a = hi + lo (hi = truncate-to-bf16, lo = RNE(a - hi));
// a*b ~= ah*bh + ah*bl + al*bh  (drop al*bl ~ 2^-16 rel).
// grid (16 b, 2 which, 8 n-slices) = 256 blocks, 512 thr = 8 waves (2M x 4N),
// wave computes 64x64 of the 128(M=k) x 256(N=d) output, K-chunks of 32 n.
// LDS planes [row][40] ushort: stride 80B -> 2-way bank aliasing = free floor.
#define PSTR 40

__global__ __launch_bounds__(512, 2) void proj_kernel(
    const float* __restrict__ pinv_a, const float* __restrict__ descr_a,
    const float* __restrict__ pinv_b, const float* __restrict__ descr_b,
    float* __restrict__ sd_a, float* __restrict__ sd_b)
{
    const int b = blockIdx.x, which = blockIdx.y, slice = blockIdx.z;
    const float* P  = (which ? pinv_b  : pinv_a)  + (size_t)b * KD * ND;
    const float* Dm = (which ? descr_b : descr_a) + (size_t)b * DD * ND;
    float* outp = (which ? sd_b : sd_a) + (size_t)b * KD * DD;

    __shared__ ushort_t Ph[KD][PSTR], Pl[KD][PSTR];
    __shared__ ushort_t Dh[DD][PSTR], Dl[DD][PSTR];

    const int tid = threadIdx.x;
    const int lane = tid & 63;
    const int wid = tid >> 6;                 // 0..7
    const int wm = wid >> 2, wn = wid & 3;    // wave tile: rows wm*64, cols wn*64
    const int fr = lane & 15;                 // fragment row/col index
    const int kg = lane >> 4;                 // k-group 0..3 (8 bf16 each)

    f32x4 acc[4][4];
    #pragma unroll
    for (int i = 0; i < 4; ++i)
        #pragma unroll
        for (int j = 0; j < 4; ++j) acc[i][j] = (f32x4){0.f, 0.f, 0.f, 0.f};

    const int n0 = slice * 1000;              // 1000 n per block = 31*32 + 8

    for (int ch = 0; ch < 32; ++ch) {
        const int nb = ch * 32;
        const int valid = (ch == 31) ? 8 : 32;

        // ---- stage + convert: 1536 slots of 8 n's (P:512, D:1024), 3 per thread
        #pragma unroll
        for (int u = 0; u < 3; ++u) {
            int row, g;
            const float* src;
            ushort_t (*dsth)[PSTR];
            ushort_t (*dstl)[PSTR];
            if (u == 0) { row = tid >> 2; g = tid & 3; src = P; dsth = Ph; dstl = Pl; }
            else {
                int s2 = tid + (u - 1) * 512;
                row = s2 >> 2; g = s2 & 3; src = Dm; dsth = Dh; dstl = Dl;
            }
            const float* p = src + (size_t)row * ND + n0 + nb + g * 8;
            float4 v0 = {0.f, 0.f, 0.f, 0.f}, v1 = {0.f, 0.f, 0.f, 0.f};
            if (g * 8 < valid)     v0 = *(const float4*)(p);
            if (g * 8 + 4 < valid) v1 = *(const float4*)(p + 4);
            float xs[8] = {v0.x, v0.y, v0.z, v0.w, v1.x, v1.y, v1.z, v1.w};
            bf16x8 hvec, lvec;
            #pragma unroll
            for (int j = 0; j < 8; ++j) {
                unsigned int bi = __float_as_uint(xs[j]);
                hvec[j] = (short)(bi >> 16);                       // truncate -> hi
                float lo = xs[j] - __uint_as_float(bi & 0xFFFF0000u);  // exact residual
                unsigned int lb = __float_as_uint(lo);
                lb = lb + 0x7FFFu + ((lb >> 16) & 1u);             // RNE to bf16
                lvec[j] = (short)(lb >> 16);
            }
            *(bf16x8*)(&dsth[row][g * 8]) = hvec;
            *(bf16x8*)(&dstl[row][g * 8]) = lvec;
        }
        __syncthreads();

        // ---- MFMA over this K=32 chunk
        bf16x8 Ah[4], Al[4];
        #pragma unroll
        for (int mi = 0; mi < 4; ++mi) {
            int r = wm * 64 + mi * 16 + fr;
            Ah[mi] = *(const bf16x8*)&Ph[r][kg * 8];
            Al[mi] = *(const bf16x8*)&Pl[r][kg * 8];
        }
        #pragma unroll
        for (int ni = 0; ni < 4; ++ni) {
            int c = wn * 64 + ni * 16 + fr;
            bf16x8 Bh = *(const bf16x8*)&Dh[c][kg * 8];
            bf16x8 Bl = *(const bf16x8*)&Dl[c][kg * 8];
            #pragma unroll
            for (int mi = 0; mi < 4; ++mi) {
                acc[mi][ni] = __builtin_amdgcn_mfma_f32_16x16x32_bf16(Ah[mi], Bh, acc[mi][ni], 0, 0, 0);
                acc[mi][ni] = __builtin_amdgcn_mfma_f32_16x16x32_bf16(Ah[mi], Bl, acc[mi][ni], 0, 0, 0);
                acc[mi][ni] = __builtin_amdgcn_mfma_f32_16x16x32_bf16(Al[mi], Bh, acc[mi][ni], 0, 0, 0);
            }
        }
        __syncthreads();
    }

    // ---- epilogue: C/D layout col=lane&15, row=(lane>>4)*4+reg (m89)
    #pragma unroll
    for (int mi = 0; mi < 4; ++mi)
        #pragma unroll
        for (int ni = 0; ni < 4; ++ni) {
            int rbase = wm * 64 + mi * 16 + kg * 4;
            int ccol  = wn * 64 + ni * 16 + fr;
            #pragma unroll
            for (int r = 0; r < 4; ++r)
                atomicAdd(&outp[(size_t)(rbase + r) * DD + ccol], acc[mi][ni][r]);
        }
}

// ---------------- K2: masks (lambda folded in).  lm_ab[b][i][k] from (gb=eb[i], ga=ea[k])
__global__ __launch_bounds__(256) void mask_kernel(
    const float* __restrict__ ea_g, const float* __restrict__ eb_g,
    float* __restrict__ lm_ab, float* __restrict__ lm_ba)
{
    const int b = blockIdx.x, tid = threadIdx.x;
    __shared__ float ta[KD], ua[KD], tb[KD], ub[KD];
    __shared__ float red[256];
    float e = (tid < KD) ? ea_g[b * KD + tid] : eb_g[b * KD + (tid - KD)];
    red[tid] = e;
    __syncthreads();
    for (int s = 128; s > 0; s >>= 1) {
        if (tid < s) red[tid] = fmaxf(red[tid], red[tid + s]);
        __syncthreads();
    }
    float is = 1.0f / red[0];
    float g = e * is;
    float den = 1.0f / (g * g + 1.0f);
    if (tid < KD) { ta[tid] = g * den; ua[tid] = den; }
    else          { tb[tid - KD] = g * den; ub[tid - KD] = den; }
    __syncthreads();
    for (int idx = tid; idx < KD * KD; idx += 256) {
        int i = idx >> 7, kc = idx & 127;
        float re = tb[i] - ta[kc], im = ub[i] - ua[kc];
        lm_ab[(size_t)b * KD * KD + idx] = LMB * (re * re + im * im);
        float re2 = ta[i] - tb[kc], im2 = ua[i] - ub[kc];
        lm_ba[(size_t)b * KD * KD + idx] = LMB * (re2 * re2 + im2 * im2);
    }
}

// ---------------- K3: Grams. m=0: AA_aa(Sa,Sa) m=1: AA_bb(Sb,Sb) m=2: AA_ba(Sb,Sa)
// AA[m][b][k][l] = sum_d X[k][d]*Y[l][d]
__global__ __attribute__((amdgpu_flat_work_group_size(1024, 1024), amdgpu_waves_per_eu(2, 8)))
void gram_kernel(
    const float* __restrict__ sd_a, const float* __restrict__ sd_b,
    float* __restrict__ AA)
{
    const int b = blockIdx.x, m = blockIdx.y;
    const float* X = (m == 0) ? sd_a : sd_b;
    const float* Y = (m == 2) ? sd_a : X;
    X += (size_t)b * KD * DD;
    Y += (size_t)b * KD * DD;
    float* outp = AA + ((size_t)m * BB + b) * KD * KD;

    __shared__ float Xs[KD][68], Ys[KD][68];
    const int tid = threadIdx.x;
    const int kq = tid >> 5, lq = tid & 31;
    float acc[4][4];
    #pragma unroll
    for (int i = 0; i < 4; ++i)
        #pragma unroll
        for (int j = 0; j < 4; ++j) acc[i][j] = 0.f;

    for (int chn = 0; chn < 4; ++chn) {
        int d0 = chn * 64;
        #pragma unroll
        for (int u = 0; u < 4; ++u) {
            int i = tid + u * 1024;           // 4096 float4s: X 2048 then Y 2048
            int half = i >> 11, rem = i & 2047;
            int r = rem >> 4, c = rem & 15;
            const float* src = half ? Y : X;
            float4 v = *(const float4*)(src + (size_t)r * DD + d0 + c * 4);
            if (half) *(float4*)&Ys[r][c * 4] = v;
            else      *(float4*)&Xs[r][c * 4] = v;
        }
        __syncthreads();
        #pragma unroll
        for (int d4 = 0; d4 < 16; ++d4) {
            float4 xv[4], yv[4];
            #pragma unroll
            for (int i = 0; i < 4; ++i) xv[i] = *(const float4*)&Xs[kq + 32 * i][d4 * 4];
            #pragma unroll
            for (int j = 0; j < 4; ++j) yv[j] = *(const float4*)&Ys[lq + 32 * j][d4 * 4];
            #pragma unroll
            for (int i = 0; i < 4; ++i)
                #pragma unroll
                for (int j = 0; j < 4; ++j)
                    acc[i][j] += xv[i].x * yv[j].x + xv[i].y * yv[j].y
                               + xv[i].z * yv[j].z + xv[i].w * yv[j].w;
        }
        __syncthreads();
    }
    #pragma unroll
    for (int i = 0; i < 4; ++i)
        #pragma unroll
        for (int j = 0; j < 4; ++j)
            outp[(size_t)(kq + 32 * i) * KD + lq + 32 * j] = acc[i][j];
}

// ---------------- K4: Gauss-Jordan in-place inversion (SPD, no pivoting).
// grid (16, 2): which=0 -> inv(AA_aa), which=1 -> inv(AA_bb). 512 threads.
__global__ __launch_bounds__(512) void invert_kernel(
    const float* __restrict__ AA, float* __restrict__ Hout)
{
    const int b = blockIdx.x, which = blockIdx.y;
    const float* src = AA + ((size_t)which * BB + b) * KD * KD;
    float* dst = Hout + ((size_t)which * BB + b) * KD * KD;
    __shared__ float A[KD][KD + 1];
    const int tid = threadIdx.x;
    for (int u = 0; u < 32; ++u) {
        int i = tid + u * 512;
        A[i >> 7][i & 127] = src[i];
    }
    __syncthreads();
    const int c = tid & 127, igrp = tid >> 7;
    for (int j = 0; j < 128; ++j) {
        float pv = 1.0f / A[j][j];
        if (tid < 128 && tid != j) A[tid][j] = -A[tid][j] * pv;  // phase 1: column j
        __syncthreads();
        float rowv = A[j][c];
        if (c != j) {                                            // phase 2: rank-1 update
            int i0 = igrp * 32;
            #pragma unroll 8
            for (int t = 0; t < 32; ++t) {
                int i = i0 + t;
                if (i != j) A[i][c] += A[i][j] * rowv;
            }
        }
        __syncthreads();
        if (tid < 128) A[j][tid] = (tid == j) ? pv : A[j][tid] * pv;  // phase 3: row j
        __syncthreads();
    }
    for (int u = 0; u < 32; ++u) {
        int i = tid + u * 512;
        dst[i] = A[i >> 7][i & 127];
    }
}

// ---------------- K5: Neumann-series solve.
// which=0 (fmap_12): H=inv(AA_aa), lm=lm_ab, r_i = AA_ba[b][i][:]
// which=1 (fmap_21): H=inv(AA_bb), lm=lm_ba, r_i = AA_ba[b][:][i]
// x_i = sum_t (-1)^t (H*lmD_i)^t H r_i ; out[b][i][l] = x_i[l]
#define NTERMS 6
__global__ __launch_bounds__(512) void solve_kernel(
    const float* __restrict__ AAba, const float* __restrict__ lm_ab,
    const float* __restrict__ lm_ba, const float* __restrict__ Hmat,
    float* __restrict__ outp)
{
    const int b = blockIdx.x, cg = blockIdx.y, which = blockIdx.z;
    const float* Hm = Hmat + ((size_t)which * BB + b) * KD * KD;
    const float* lm = (which ? lm_ba : lm_ab) + (size_t)b * KD * KD;
    const float* Rs = AAba + (size_t)b * KD * KD;
    float* op = outp + ((size_t)which * BB + b) * KD * KD;
    const int i0 = cg * 32;

    __shared__ float Hs[KD][132];       // Hs[d][l]; H symmetric so Hs[d][l] == H[l][d]
    __shared__ float Zc[2][32][132];    // Zc[buf][ic][d]
    __shared__ float lms[32][132];      // lms[ic][l]

    const int tid = threadIdx.x;
    const int rq = tid & 31;            // rows l = rq*4 + rr
    const int cq = tid >> 5;            // 0..15, cols ic = cq*2 + cc

    #pragma unroll
    for (int u = 0; u < 8; ++u) {
        int idx = tid + u * 512;
        int d = idx >> 5, l4 = idx & 31;
        *(float4*)&Hs[d][l4 * 4] = *(const float4*)(Hm + (size_t)d * KD + l4 * 4);
    }
    #pragma unroll
    for (int u = 0; u < 8; ++u) {
        int idx = tid + u * 512;
        int ic = idx >> 7, l = idx & 127;
        lms[ic][l] = lm[(size_t)(i0 + ic) * KD + l];
    }
    if (which == 0) {
        #pragma unroll
        for (int u = 0; u < 8; ++u) {
            int idx = tid + u * 512;
            int ic = idx >> 7, d = idx & 127;
            Zc[0][ic][d] = Rs[(size_t)(i0 + ic) * KD + d];
        }
    } else {
        #pragma unroll
        for (int u = 0; u < 8; ++u) {
            int idx = tid + u * 512;
            int d = idx >> 5, ic = idx & 31;
            Zc[0][ic][d] = Rs[(size_t)d * KD + i0 + ic];
        }
    }
    __syncthreads();

    float xacc[4][2];
    #pragma unroll
    for (int rr = 0; rr < 4; ++rr) { xacc[rr][0] = 0.f; xacc[rr][1] = 0.f; }
    int cur = 0;
    for (int t = 0; t < NTERMS; ++t) {
        float zr[4][2];
        #pragma unroll
        for (int rr = 0; rr < 4; ++rr) { zr[rr][0] = 0.f; zr[rr][1] = 0.f; }
        #pragma unroll 8
        for (int d4 = 0; d4 < 32; ++d4) {
            float4 hv[4];
            #pragma unroll
            for (int dd = 0; dd < 4; ++dd)
                hv[dd] = *(const float4*)&Hs[d4 * 4 + dd][rq * 4];
            float4 wv[2];
            #pragma unroll
            for (int cc = 0; cc < 2; ++cc)
                wv[cc] = *(const float4*)&Zc[cur][cq * 2 + cc][d4 * 4];
            #pragma unroll
            for (int cc = 0; cc < 2; ++cc) {
                zr[0][cc] += hv[0].x * wv[cc].x + hv[1].x * wv[cc].y + hv[2].x * wv[cc].z + hv[3].x * wv[cc].w;
                zr[1][cc] += hv[0].y * wv[cc].x + hv[1].y * wv[cc].y + hv[2].y * wv[cc].z + hv[3].y * wv[cc].w;
                zr[2][cc] += hv[0].z * wv[cc].x + hv[1].z * wv[cc].y + hv[2].z * wv[cc].z + hv[3].z * wv[cc].w;
                zr[3][cc] += hv[0].w * wv[cc].x + hv[1].w * wv[cc].y + hv[2].w * wv[cc].z + hv[3].w * wv[cc].w;
            }
        }
        const float s = (t & 1) ? -1.f : 1.f;
        #pragma unroll
        for (int rr = 0; rr < 4; ++rr) {
            xacc[rr][0] += s * zr[rr][0];
            xacc[rr][1] += s * zr[rr][1];
        }
        if (t + 1 < NTERMS) {
            #pragma unroll
            for (int cc = 0; cc < 2; ++cc) {
                float4 lmv = *(const float4*)&lms[cq * 2 + cc][rq * 4];
                float4 w;
                w.x = lmv.x * zr[0][cc];
                w.y = lmv.y * zr[1][cc];
                w.z = lmv.z * zr[2][cc];
                w.w = lmv.w * zr[3][cc];
                *(float4*)&Zc[cur ^ 1][cq * 2 + cc][rq * 4] = w;
            }
            __syncthreads();
            cur ^= 1;
        }
    }
    #pragma unroll
    for (int cc = 0; cc < 2; ++cc) {
        float4 o;
        o.x = xacc[0][cc]; o.y = xacc[1][cc]; o.z = xacc[2][cc]; o.w = xacc[3][cc];
        *(float4*)(op + (size_t)(i0 + cq * 2 + cc) * KD + rq * 4) = o;
    }
}

extern "C" void kernel_launch(void* const* d_in, const int* in_sizes, int n_in,
                              void* d_out, int out_size, void* d_ws, size_t ws_size,
                              hipStream_t stream) {
    (void)in_sizes; (void)n_in; (void)out_size; (void)ws_size;
    const float* evals_a = (const float*)d_in[0];
    const float* pinv_a  = (const float*)d_in[1];
    const float* descr_a = (const float*)d_in[2];
    const float* evals_b = (const float*)d_in[3];
    const float* pinv_b  = (const float*)d_in[4];
    const float* descr_b = (const float*)d_in[5];
    float* out = (float*)d_out;
    float* ws = (float*)d_ws;

    const size_t SD = (size_t)BB * KD * DD;   // 524288
    const size_t MM = (size_t)BB * KD * KD;   // 262144
    float* sd_a  = ws;
    float* sd_b  = sd_a + SD;
    float* AA    = sd_b + SD;        // 3*MM: [0]=AA_aa [1]=AA_bb [2]=AA_ba
    float* lm_ab = AA + 3 * MM;
    float* lm_ba = lm_ab + MM;
    float* Hm    = lm_ba + MM;       // 2*MM

    hipMemsetAsync(sd_a, 0, 2 * SD * sizeof(float), stream);
    proj_kernel<<<dim3(BB, 2, 8), 512, 0, stream>>>(pinv_a, descr_a, pinv_b, descr_b, sd_a, sd_b);
    mask_kernel<<<dim3(BB), 256, 0, stream>>>(evals_a, evals_b, lm_ab, lm_ba);
    gram_kernel<<<dim3(BB, 3), 1024, 0, stream>>>(sd_a, sd_b, AA);
    invert_kernel<<<dim3(BB, 2), 512, 0, stream>>>(AA, Hm);
    solve_kernel<<<dim3(BB, 4, 2), 512, 0, stream>>>(AA + 2 * MM, lm_ab, lm_ba, Hm, out);
}

// Round 6
// 318.567 us; speedup vs baseline: 31.8321x; 2.0284x over previous
//
#include <hip/hip_runtime.h>

#define BB 16
#define KD 128
#define ND 8000
#define DD 256
#define LMB 1000.0f

typedef __attribute__((ext_vector_type(8))) short bf16x8;
typedef __attribute__((ext_vector_type(4))) short bf16x4;
typedef __attribute__((ext_vector_type(4))) float f32x4;
typedef unsigned short ushort_t;

// exact split: x = hi + lo (hi = truncate-to-bf16, lo = RNE(x - hi))
__device__ inline void split_bf16(float x, ushort_t& h, ushort_t& l) {
    unsigned int bi = __float_as_uint(x);
    h = (ushort_t)(bi >> 16);
    float lo = x - __uint_as_float(bi & 0xFFFF0000u);
    unsigned int lb = __float_as_uint(lo);
    lb = lb + 0x7FFFu + ((lb >> 16) & 1u);
    l = (ushort_t)(lb >> 16);
}

// ---------------- K1: projection  sd[b][k][d] = sum_n pinv[b][k][n]*descr[b][d][n]
// Split-bf16 MFMA (a*b ~= ah*bh + ah*bl + al*bh). grid (16,2,8), 512 thr = 8 waves.
#define PSTR 40

__global__ __launch_bounds__(512, 2) void proj_kernel(
    const float* __restrict__ pinv_a, const float* __restrict__ descr_a,
    const float* __restrict__ pinv_b, const float* __restrict__ descr_b,
    float* __restrict__ sd_a, float* __restrict__ sd_b)
{
    const int b = blockIdx.x, which = blockIdx.y, slice = blockIdx.z;
    const float* P  = (which ? pinv_b  : pinv_a)  + (size_t)b * KD * ND;
    const float* Dm = (which ? descr_b : descr_a) + (size_t)b * DD * ND;
    float* outp = (which ? sd_b : sd_a) + (size_t)b * KD * DD;

    __shared__ ushort_t Ph[KD][PSTR], Pl[KD][PSTR];
    __shared__ ushort_t Dh[DD][PSTR], Dl[DD][PSTR];

    const int tid = threadIdx.x;
    const int lane = tid & 63;
    const int wid = tid >> 6;
    const int wm = wid >> 2, wn = wid & 3;
    const int fr = lane & 15;
    const int kg = lane >> 4;

    f32x4 acc[4][4];
    #pragma unroll
    for (int i = 0; i < 4; ++i)
        #pragma unroll
        for (int j = 0; j < 4; ++j) acc[i][j] = (f32x4){0.f, 0.f, 0.f, 0.f};

    const int n0 = slice * 1000;

    for (int ch = 0; ch < 32; ++ch) {
        const int nb = ch * 32;
        const int valid = (ch == 31) ? 8 : 32;

        #pragma unroll
        for (int u = 0; u < 3; ++u) {
            int row, g;
            const float* src;
            ushort_t (*dsth)[PSTR];
            ushort_t (*dstl)[PSTR];
            if (u == 0) { row = tid >> 2; g = tid & 3; src = P; dsth = Ph; dstl = Pl; }
            else {
                int s2 = tid + (u - 1) * 512;
                row = s2 >> 2; g = s2 & 3; src = Dm; dsth = Dh; dstl = Dl;
            }
            const float* p = src + (size_t)row * ND + n0 + nb + g * 8;
            float4 v0 = {0.f, 0.f, 0.f, 0.f}, v1 = {0.f, 0.f, 0.f, 0.f};
            if (g * 8 < valid)     v0 = *(const float4*)(p);
            if (g * 8 + 4 < valid) v1 = *(const float4*)(p + 4);
            float xs[8] = {v0.x, v0.y, v0.z, v0.w, v1.x, v1.y, v1.z, v1.w};
            bf16x8 hvec, lvec;
            #pragma unroll
            for (int j = 0; j < 8; ++j) {
                ushort_t hh, ll;
                split_bf16(xs[j], hh, ll);
                hvec[j] = (short)hh; lvec[j] = (short)ll;
            }
            *(bf16x8*)(&dsth[row][g * 8]) = hvec;
            *(bf16x8*)(&dstl[row][g * 8]) = lvec;
        }
        __syncthreads();

        bf16x8 Ah[4], Al[4];
        #pragma unroll
        for (int mi = 0; mi < 4; ++mi) {
            int r = wm * 64 + mi * 16 + fr;
            Ah[mi] = *(const bf16x8*)&Ph[r][kg * 8];
            Al[mi] = *(const bf16x8*)&Pl[r][kg * 8];
        }
        #pragma unroll
        for (int ni = 0; ni < 4; ++ni) {
            int c = wn * 64 + ni * 16 + fr;
            bf16x8 Bh = *(const bf16x8*)&Dh[c][kg * 8];
            bf16x8 Bl = *(const bf16x8*)&Dl[c][kg * 8];
            #pragma unroll
            for (int mi = 0; mi < 4; ++mi) {
                acc[mi][ni] = __builtin_amdgcn_mfma_f32_16x16x32_bf16(Ah[mi], Bh, acc[mi][ni], 0, 0, 0);
                acc[mi][ni] = __builtin_amdgcn_mfma_f32_16x16x32_bf16(Ah[mi], Bl, acc[mi][ni], 0, 0, 0);
                acc[mi][ni] = __builtin_amdgcn_mfma_f32_16x16x32_bf16(Al[mi], Bh, acc[mi][ni], 0, 0, 0);
            }
        }
        __syncthreads();
    }

    #pragma unroll
    for (int mi = 0; mi < 4; ++mi)
        #pragma unroll
        for (int ni = 0; ni < 4; ++ni) {
            int rbase = wm * 64 + mi * 16 + kg * 4;
            int ccol  = wn * 64 + ni * 16 + fr;
            #pragma unroll
            for (int r = 0; r < 4; ++r)
                atomicAdd(&outp[(size_t)(rbase + r) * DD + ccol], acc[mi][ni][r]);
        }
}

// ---------------- K2: masks (lambda folded in)
__global__ __launch_bounds__(256) void mask_kernel(
    const float* __restrict__ ea_g, const float* __restrict__ eb_g,
    float* __restrict__ lm_ab, float* __restrict__ lm_ba)
{
    const int b = blockIdx.x, tid = threadIdx.x;
    __shared__ float ta[KD], ua[KD], tb[KD], ub[KD];
    __shared__ float red[256];
    float e = (tid < KD) ? ea_g[b * KD + tid] : eb_g[b * KD + (tid - KD)];
    red[tid] = e;
    __syncthreads();
    for (int s = 128; s > 0; s >>= 1) {
        if (tid < s) red[tid] = fmaxf(red[tid], red[tid + s]);
        __syncthreads();
    }
    float is = 1.0f / red[0];
    float g = e * is;
    float den = 1.0f / (g * g + 1.0f);
    if (tid < KD) { ta[tid] = g * den; ua[tid] = den; }
    else          { tb[tid - KD] = g * den; ub[tid - KD] = den; }
    __syncthreads();
    for (int idx = tid; idx < KD * KD; idx += 256) {
        int i = idx >> 7, kc = idx & 127;
        float re = tb[i] - ta[kc], im = ub[i] - ua[kc];
        lm_ab[(size_t)b * KD * KD + idx] = LMB * (re * re + im * im);
        float re2 = ta[i] - tb[kc], im2 = ua[i] - ub[kc];
        lm_ba[(size_t)b * KD * KD + idx] = LMB * (re2 * re2 + im2 * im2);
    }
}

// ---------------- K3: Grams via split-bf16 MFMA. m=0: (Sa,Sa) m=1: (Sb,Sb) m=2: (Sb,Sa)
// AA[m][b][k][l] = sum_d X[k][d]*Y[l][d]. grid (16,3), 512 thr = 8 waves (2M x 4N),
// wave tile 64(k) x 32(l), d-chunks of 64. LDS stride 68 ushorts -> 2 lanes/bank (free).
#define GSTR 68
__global__ __launch_bounds__(512, 2) void gram_kernel(
    const float* __restrict__ sd_a, const float* __restrict__ sd_b,
    float* __restrict__ AA)
{
    const int b = blockIdx.x, m = blockIdx.y;
    const float* X = (m == 0) ? sd_a : sd_b;
    const float* Y = (m == 2) ? sd_a : X;
    X += (size_t)b * KD * DD;
    Y += (size_t)b * KD * DD;
    float* outp = AA + ((size_t)m * BB + b) * KD * KD;

    __shared__ ushort_t Xh[KD][GSTR], Xl[KD][GSTR];
    __shared__ ushort_t Yh[KD][GSTR], Yl[KD][GSTR];

    const int tid = threadIdx.x;
    const int lane = tid & 63;
    const int wid = tid >> 6;
    const int wm = wid >> 2, wn = wid & 3;
    const int fr = lane & 15;
    const int kg = lane >> 4;

    f32x4 acc[4][2];
    #pragma unroll
    for (int i = 0; i < 4; ++i)
        #pragma unroll
        for (int j = 0; j < 2; ++j) acc[i][j] = (f32x4){0.f, 0.f, 0.f, 0.f};

    for (int d0 = 0; d0 < DD; d0 += 64) {
        // stage + convert: X and Y each 128x64 = 2048 float4 slots
        #pragma unroll
        for (int u = 0; u < 8; ++u) {
            int idx = tid + (u & 3) * 512;
            int r = idx >> 4, c4 = idx & 15;
            const float* src = (u < 4) ? X : Y;
            float4 v = *(const float4*)(src + (size_t)r * DD + d0 + c4 * 4);
            float xs[4] = {v.x, v.y, v.z, v.w};
            bf16x4 hv, lv;
            #pragma unroll
            for (int q = 0; q < 4; ++q) {
                ushort_t hh, ll;
                split_bf16(xs[q], hh, ll);
                hv[q] = (short)hh; lv[q] = (short)ll;
            }
            if (u < 4) {
                *(bf16x4*)&Xh[r][c4 * 4] = hv;
                *(bf16x4*)&Xl[r][c4 * 4] = lv;
            } else {
                *(bf16x4*)&Yh[r][c4 * 4] = hv;
                *(bf16x4*)&Yl[r][c4 * 4] = lv;
            }
        }
        __syncthreads();

        #pragma unroll
        for (int kk = 0; kk < 2; ++kk) {
            const int co = kk * 32 + kg * 8;
            bf16x8 Ah[4], Al[4];
            #pragma unroll
            for (int mi = 0; mi < 4; ++mi) {
                int r = wm * 64 + mi * 16 + fr;
                Ah[mi] = *(const bf16x8*)&Xh[r][co];
                Al[mi] = *(const bf16x8*)&Xl[r][co];
            }
            #pragma unroll
            for (int ni = 0; ni < 2; ++ni) {
                int c = wn * 32 + ni * 16 + fr;
                bf16x8 Bh = *(const bf16x8*)&Yh[c][co];
                bf16x8 Bl = *(const bf16x8*)&Yl[c][co];
                #pragma unroll
                for (int mi = 0; mi < 4; ++mi) {
                    acc[mi][ni] = __builtin_amdgcn_mfma_f32_16x16x32_bf16(Ah[mi], Bh, acc[mi][ni], 0, 0, 0);
                    acc[mi][ni] = __builtin_amdgcn_mfma_f32_16x16x32_bf16(Ah[mi], Bl, acc[mi][ni], 0, 0, 0);
                    acc[mi][ni] = __builtin_amdgcn_mfma_f32_16x16x32_bf16(Al[mi], Bh, acc[mi][ni], 0, 0, 0);
                }
            }
        }
        __syncthreads();
    }

    #pragma unroll
    for (int mi = 0; mi < 4; ++mi)
        #pragma unroll
        for (int ni = 0; ni < 2; ++ni) {
            int rbase = wm * 64 + mi * 16 + kg * 4;
            int ccol  = wn * 32 + ni * 16 + fr;
            #pragma unroll
            for (int rr = 0; rr < 4; ++rr)
                outp[(size_t)(rbase + rr) * KD + ccol] = acc[mi][ni][rr];
        }
}

// ---------------- K4: register-resident Gauss-Jordan inversion (SPD, no pivoting).
// grid (16,2), 512 thr. Thread (rb=tid>>5, cg=tid&31) owns rows rb*8..+7, cols cg*4..+3
// in f32x4 Areg[8]. Pivot row/col broadcast via parity-double-buffered LDS; 1 barrier/pivot.
__global__ __launch_bounds__(512, 2) void invert_kernel(
    const float* __restrict__ AA, float* __restrict__ Hout)
{
    const int b = blockIdx.x, which = blockIdx.y;
    const float* src = AA + ((size_t)which * BB + b) * KD * KD;
    float* dst = Hout + ((size_t)which * BB + b) * KD * KD;

    __shared__ float rowbuf[2][KD];
    __shared__ float colbuf[2][KD];

    const int tid = threadIdx.x;
    const int rb = tid >> 5;
    const int cg = tid & 31;

    f32x4 Areg[8];
    #pragma unroll
    for (int r = 0; r < 8; ++r)
        Areg[r] = *(const f32x4*)(src + (size_t)(rb * 8 + r) * KD + cg * 4);

    if (rb == 0) *(f32x4*)&rowbuf[0][cg * 4] = Areg[0];
    if (cg == 0) {
        #pragma unroll
        for (int r = 0; r < 8; ++r) colbuf[0][rb * 8 + r] = Areg[r].x;
    }
    __syncthreads();

    for (int j = 0; j < KD; ++j) {
        const int cur = j & 1, nxt = cur ^ 1;
        const int jrb = j >> 3, jr = j & 7, jcg = j >> 2, jc = j & 3;
        const float pv = 1.0f / rowbuf[cur][j];
        const f32x4 orow = *(const f32x4*)&rowbuf[cur][cg * 4];
        const f32x4 prow = orow * pv;
        const bool mycg = (cg == jcg);
        const bool myrb = (rb == jrb);

        #pragma unroll
        for (int r = 0; r < 8; ++r) {
            const float cm = colbuf[cur][rb * 8 + r];
            const float cmul = -cm * pv;
            const bool piv = myrb && (r == jr);
            f32x4 nv;
            nv.x = piv ? prow.x : fmaf(cmul, orow.x, Areg[r].x);
            nv.y = piv ? prow.y : fmaf(cmul, orow.y, Areg[r].y);
            nv.z = piv ? prow.z : fmaf(cmul, orow.z, Areg[r].z);
            nv.w = piv ? prow.w : fmaf(cmul, orow.w, Areg[r].w);
            if (mycg) {
                const float fixv = piv ? pv : cmul;
                nv.x = (jc == 0) ? fixv : nv.x;
                nv.y = (jc == 1) ? fixv : nv.y;
                nv.z = (jc == 2) ? fixv : nv.z;
                nv.w = (jc == 3) ? fixv : nv.w;
            }
            Areg[r] = nv;
        }

        if (j + 1 < KD) {
            const int njrb = (j + 1) >> 3, njr = (j + 1) & 7;
            const int njcg = (j + 1) >> 2, njc = (j + 1) & 3;
            if (rb == njrb) {
                #pragma unroll
                for (int r = 0; r < 8; ++r)
                    if (r == njr) *(f32x4*)&rowbuf[nxt][cg * 4] = Areg[r];
            }
            if (cg == njcg) {
                #pragma unroll
                for (int r = 0; r < 8; ++r) {
                    const f32x4 a = Areg[r];
                    const float e = (njc == 0) ? a.x : (njc == 1) ? a.y : (njc == 2) ? a.z : a.w;
                    colbuf[nxt][rb * 8 + r] = e;
                }
            }
        }
        __syncthreads();
    }

    #pragma unroll
    for (int r = 0; r < 8; ++r)
        *(f32x4*)(dst + (size_t)(rb * 8 + r) * KD + cg * 4) = Areg[r];
}

// ---------------- K5: Neumann-series solve.
#define NTERMS 6
__global__ __launch_bounds__(512) void solve_kernel(
    const float* __restrict__ AAba, const float* __restrict__ lm_ab,
    const float* __restrict__ lm_ba, const float* __restrict__ Hmat,
    float* __restrict__ outp)
{
    const int b = blockIdx.x, cg = blockIdx.y, which = blockIdx.z;
    const float* Hm = Hmat + ((size_t)which * BB + b) * KD * KD;
    const float* lm = (which ? lm_ba : lm_ab) + (size_t)b * KD * KD;
    const float* Rs = AAba + (size_t)b * KD * KD;
    float* op = outp + ((size_t)which * BB + b) * KD * KD;
    const int i0 = cg * 32;

    __shared__ float Hs[KD][132];
    __shared__ float Zc[2][32][132];
    __shared__ float lms[32][132];

    const int tid = threadIdx.x;
    const int rq = tid & 31;
    const int cq = tid >> 5;

    #pragma unroll
    for (int u = 0; u < 8; ++u) {
        int idx = tid + u * 512;
        int d = idx >> 5, l4 = idx & 31;
        *(float4*)&Hs[d][l4 * 4] = *(const float4*)(Hm + (size_t)d * KD + l4 * 4);
    }
    #pragma unroll
    for (int u = 0; u < 8; ++u) {
        int idx = tid + u * 512;
        int ic = idx >> 7, l = idx & 127;
        lms[ic][l] = lm[(size_t)(i0 + ic) * KD + l];
    }
    if (which == 0) {
        #pragma unroll
        for (int u = 0; u < 8; ++u) {
            int idx = tid + u * 512;
            int ic = idx >> 7, d = idx & 127;
            Zc[0][ic][d] = Rs[(size_t)(i0 + ic) * KD + d];
        }
    } else {
        #pragma unroll
        for (int u = 0; u < 8; ++u) {
            int idx = tid + u * 512;
            int d = idx >> 5, ic = idx & 31;
            Zc[0][ic][d] = Rs[(size_t)d * KD + i0 + ic];
        }
    }
    __syncthreads();

    float xacc[4][2];
    #pragma unroll
    for (int rr = 0; rr < 4; ++rr) { xacc[rr][0] = 0.f; xacc[rr][1] = 0.f; }
    int cur = 0;
    for (int t = 0; t < NTERMS; ++t) {
        float zr[4][2];
        #pragma unroll
        for (int rr = 0; rr < 4; ++rr) { zr[rr][0] = 0.f; zr[rr][1] = 0.f; }
        #pragma unroll 8
        for (int d4 = 0; d4 < 32; ++d4) {
            float4 hv[4];
            #pragma unroll
            for (int dd = 0; dd < 4; ++dd)
                hv[dd] = *(const float4*)&Hs[d4 * 4 + dd][rq * 4];
            float4 wv[2];
            #pragma unroll
            for (int cc = 0; cc < 2; ++cc)
                wv[cc] = *(const float4*)&Zc[cur][cq * 2 + cc][d4 * 4];
            #pragma unroll
            for (int cc = 0; cc < 2; ++cc) {
                zr[0][cc] += hv[0].x * wv[cc].x + hv[1].x * wv[cc].y + hv[2].x * wv[cc].z + hv[3].x * wv[cc].w;
                zr[1][cc] += hv[0].y * wv[cc].x + hv[1].y * wv[cc].y + hv[2].y * wv[cc].z + hv[3].y * wv[cc].w;
                zr[2][cc] += hv[0].z * wv[cc].x + hv[1].z * wv[cc].y + hv[2].z * wv[cc].z + hv[3].z * wv[cc].w;
                zr[3][cc] += hv[0].w * wv[cc].x + hv[1].w * wv[cc].y + hv[2].w * wv[cc].z + hv[3].w * wv[cc].w;
            }
        }
        const float s = (t & 1) ? -1.f : 1.f;
        #pragma unroll
        for (int rr = 0; rr < 4; ++rr) {
            xacc[rr][0] += s * zr[rr][0];
            xacc[rr][1] += s * zr[rr][1];
        }
        if (t + 1 < NTERMS) {
            #pragma unroll
            for (int cc = 0; cc < 2; ++cc) {
                float4 lmv = *(const float4*)&lms[cq * 2 + cc][rq * 4];
                float4 w;
                w.x = lmv.x * zr[0][cc];
                w.y = lmv.y * zr[1][cc];
                w.z = lmv.z * zr[2][cc];
                w.w = lmv.w * zr[3][cc];
                *(float4*)&Zc[cur ^ 1][cq * 2 + cc][rq * 4] = w;
            }
            __syncthreads();
            cur ^= 1;
        }
    }
    #pragma unroll
    for (int cc = 0; cc < 2; ++cc) {
        float4 o;
        o.x = xacc[0][cc]; o.y = xacc[1][cc]; o.z = xacc[2][cc]; o.w = xacc[3][cc];
        *(float4*)(op + (size_t)(i0 + cq * 2 + cc) * KD + rq * 4) = o;
    }
}

extern "C" void kernel_launch(void* const* d_in, const int* in_sizes, int n_in,
                              void* d_out, int out_size, void* d_ws, size_t ws_size,
                              hipStream_t stream) {
    (void)in_sizes; (void)n_in; (void)out_size; (void)ws_size;
    const float* evals_a = (const float*)d_in[0];
    const float* pinv_a  = (const float*)d_in[1];
    const float* descr_a = (const float*)d_in[2];
    const float* evals_b = (const float*)d_in[3];
    const float* pinv_b  = (const float*)d_in[4];
    const float* descr_b = (const float*)d_in[5];
    float* out = (float*)d_out;
    float* ws = (float*)d_ws;

    const size_t SD = (size_t)BB * KD * DD;   // 524288
    const size_t MM = (size_t)BB * KD * KD;   // 262144
    float* sd_a  = ws;
    float* sd_b  = sd_a + SD;
    float* AA    = sd_b + SD;        // 3*MM: [0]=AA_aa [1]=AA_bb [2]=AA_ba
    float* lm_ab = AA + 3 * MM;
    float* lm_ba = lm_ab + MM;
    float* Hm    = lm_ba + MM;       // 2*MM

    hipMemsetAsync(sd_a, 0, 2 * SD * sizeof(float), stream);
    proj_kernel<<<dim3(BB, 2, 8), 512, 0, stream>>>(pinv_a, descr_a, pinv_b, descr_b, sd_a, sd_b);
    mask_kernel<<<dim3(BB), 256, 0, stream>>>(evals_a, evals_b, lm_ab, lm_ba);
    gram_kernel<<<dim3(BB, 3), 512, 0, stream>>>(sd_a, sd_b, AA);
    invert_kernel<<<dim3(BB, 2), 512, 0, stream>>>(AA, Hm);
    solve_kernel<<<dim3(BB, 4, 2), 512, 0, stream>>>(AA + 2 * MM, lm_ab, lm_ba, Hm, out);
}